// Round 10
// baseline (642.595 us; speedup 1.0000x reference)
//
#include <hip/hip_runtime.h>
#include <hip/hip_bf16.h>
#include <math.h>

#define HEADS  8
#define TT     32
#define DMODEL 512
#define HWSZ   1024
#define TSTRIDE (HWSZ*DMODEL)

#define NQKV (3*DMODEL*DMODEL)   // 786432
#define NOUT (DMODEL*DMODEL)     // 262144
#define NTAB 512

typedef __attribute__((ext_vector_type(8)))  short bf16x8;
typedef __attribute__((ext_vector_type(16))) float f32x16;
typedef __attribute__((ext_vector_type(4)))  short s16x4;

__device__ __forceinline__ unsigned short f2bf(float f) {   // RNE f32->bf16
    unsigned int u = __builtin_bit_cast(unsigned int, f);
    u += 0x7FFFu + ((u >> 16) & 1u);
    return (unsigned short)(u >> 16);
}

__device__ __forceinline__ f32x16 fz16() {
    f32x16 v = {0.f,0.f,0.f,0.f,0.f,0.f,0.f,0.f,0.f,0.f,0.f,0.f,0.f,0.f,0.f,0.f};
    return v;
}

// ---------------- prep: weights -> bf16 MFMA32 B-fragment order + rope tables --
// B-frag layout (32x32x16): lane l holds B[k = ks*16 + (l>>5)*8 + i][n = ct*32 + (l&31)]
// 1KB block per (ct, ks): element ((ct*32 + ks)*64 + lane)*8 + i
__global__ __launch_bounds__(256)
void taa_prep(const float* __restrict__ wqkv, const float* __restrict__ wout,
              unsigned short* __restrict__ ws) {
    long i = (long)blockIdx.x * 256 + threadIdx.x;
    unsigned short* wqf = ws;
    unsigned short* wof = ws + NQKV;
    float* cs = (float*)(wof + NOUT);
    float* sn = cs + NTAB;
    if (i < NQKV) {
        int i8 = (int)(i & 7), lane = (int)((i >> 3) & 63), blk = (int)(i >> 9);
        int ks = blk & 31, ct = blk >> 5;          // ct < 48
        int n = ct * 32 + (lane & 31);
        int k = ks * 16 + (lane >> 5) * 8 + i8;
        wqf[i] = f2bf(wqkv[(long)k * 1536 + n]);
    } else if (i < NQKV + NOUT) {
        long j = i - NQKV;
        int i8 = (int)(j & 7), lane = (int)((j >> 3) & 63), blk = (int)(j >> 9);
        int ks = blk & 31, ct = blk >> 5;          // ct < 16
        int n = ct * 32 + (lane & 31);
        int k = ks * 16 + (lane >> 5) * 8 + i8;
        wof[j] = f2bf(wout[(long)k * 512 + n]);
    } else if (i < NQKV + NOUT + NTAB) {
        int j = (int)(i - NQKV - NOUT);
        int t = j >> 4, f = j & 15;
        float inv = powf(10000.f, -(float)(2 * f) / 32.f);
        float sv, cv;
        sincosf((float)t * inv, &sv, &cv);
        cs[j] = cv; sn[j] = sv;
    }
}

// ---------------- LDS layout (bytes), 1 group per block ------------------------
// X  [32][512]bf16 swizzled rows (1024B stride)   32768
// Q  [2h][32][64]bf16 128B stride, RS swizzle      8192
// K  same                                          8192
// V^T[2h][64 d][32 t]bf16 64B stride, VS swizzle   8192
// PV [32][128]bf16 256B stride, PS swizzle         8192
// cos/sin f32[512] each                            4096
#define X_OFF  0
#define Q_OFF  32768
#define K_OFF  40960
#define V_OFF  49152
#define PV_OFF 57344
#define CS_OFF 65536
#define SN_OFF 67584
#define LDS_SZ 69632

#define XS(r,cB) (X_OFF + ((r)<<10) + ((cB) ^ (((r)&7)<<4)))
#define RS(base,r,cB) ((base) + ((r)<<7) + ((cB) ^ (((r)&7)<<4)))
#define VS(base,d,cB) ((base) + ((d)<<6) + ((cB) ^ (((d)&7)<<3)))
#define PS(r,cB) (PV_OFF + ((r)<<8) + ((cB) ^ (((r)&7)<<4)))

#define MFMA32(a, b, c) __builtin_amdgcn_mfma_f32_32x32x16_bf16((a), (b), (c), 0, 0, 0)

// 256-thread block (4 waves): escapes the 128-VGPR heuristic cap observed on
// every 512-thread variant (m97-style 256-thread GEMMs get 164 VGPRs).
// 68KB LDS -> 2 blocks/CU (8 waves/CU).
__global__ __launch_bounds__(256)
void taa_main(const float* __restrict__ x,
              const unsigned short* __restrict__ ws,
              const float* __restrict__ b_out,
              float* __restrict__ out) {
    extern __shared__ __align__(16) unsigned char smem[];

    const unsigned short* wqf = ws;
    const unsigned short* wof = ws + NQKV;
    const float* cs_gl = (const float*)(wof + NOUT);
    const float* sn_gl = cs_gl + NTAB;

    const int tid  = threadIdx.x;
    const int lane = tid & 63;
    const int wv   = tid >> 6;                 // wave 0..3
    const int hf   = lane >> 5;                // half-wave 0/1
    const int tq   = lane & 31;

    const int n  = blockIdx.x;                 // group id 0..2047
    const long long base = ((long long)(n >> 10) * (TT * HWSZ) + (n & 1023)) * DMODEL;

    float* cs_l = (float*)(smem + CS_OFF);
    float* sn_l = (float*)(smem + SN_OFF);
    for (int i = tid; i < NTAB; i += 256) { cs_l[i] = cs_gl[i]; sn_l[i] = sn_gl[i]; }

    // ---- stage x: fp32 global -> bf16 swizzled LDS (32x512) ----
    for (int idx = tid; idx < 2048; idx += 256) {
        int r  = idx >> 6;
        int c8 = idx & 63;
        const float4* src = (const float4*)(x + base + (long long)r * TSTRIDE + c8 * 8);
        float4 f0 = src[0], f1 = src[1];
        s16x4 lo, hi;
        lo[0] = (short)f2bf(f0.x); lo[1] = (short)f2bf(f0.y);
        lo[2] = (short)f2bf(f0.z); lo[3] = (short)f2bf(f0.w);
        hi[0] = (short)f2bf(f1.x); hi[1] = (short)f2bf(f1.y);
        hi[2] = (short)f2bf(f1.z); hi[3] = (short)f2bf(f1.w);
        int a = XS(r, c8 * 16);
        *(s16x4*)(smem + a)     = lo;
        *(s16x4*)(smem + a + 8) = hi;
    }

    f32x16 oac[4];                             // out-proj acc, col-tile ct = wv + 4*j
    oac[0] = fz16(); oac[1] = fz16(); oac[2] = fz16(); oac[3] = fz16();

    __syncthreads();

    // wave's fixed role: head-in-pair hh, d-half dh
    const int hh = wv >> 1;
    const int dh = wv & 1;

    for (int it = 0; it < 4; ++it) {
        const int hd = it * 2 + hh;            // global head

        // ===== qkv: one A-stream feeds 3 MFMA chains (q,k,v) per K-step =======
        {
            const unsigned short* pq = wqf + ((long)((      hd * 2 + dh) * 32)) * 512 + lane * 8;
            const unsigned short* pk = wqf + ((long)((16 + hd * 2 + dh) * 32)) * 512 + lane * 8;
            const unsigned short* pv = wqf + ((long)((32 + hd * 2 + dh) * 32)) * 512 + lane * 8;
            f32x16 aq = fz16(), ak = fz16(), av = fz16();
            #pragma unroll 4
            for (int ks = 0; ks < 32; ++ks) {
                bf16x8 a   = *(const bf16x8*)(smem + XS(tq, ks * 32 + hf * 16));
                bf16x8 wq_ = *(const bf16x8*)(pq + (long)ks * 512);
                bf16x8 wk_ = *(const bf16x8*)(pk + (long)ks * 512);
                bf16x8 wv_ = *(const bf16x8*)(pv + (long)ks * 512);
                aq = MFMA32(a, wq_, aq);
                ak = MFMA32(a, wk_, ak);
                av = MFMA32(a, wv_, av);
            }
            // epilogue: q,k (RoPE on d-half 0), v -> V^T
            int qb = Q_OFF + hh * 4096;
            int kb = K_OFF + hh * 4096;
            if (dh == 0) {                     // dims 0..31: all rotary
                #pragma unroll
                for (int r = 0; r < 16; ++r) {
                    int t = (r & 3) + 8 * (r >> 2) + 4 * hf;
                    float cv = cs_l[t * 16 + (tq >> 1)];
                    float sv = sn_l[t * 16 + (tq >> 1)];
                    float vq = aq[r], pq2 = __shfl_xor(vq, 1, 64);
                    float rq = (tq & 1) ? (vq * cv + pq2 * sv) : (vq * cv - pq2 * sv);
                    *(unsigned short*)(smem + RS(qb, t, tq * 2)) = f2bf(rq);
                    float vk = ak[r], pk2 = __shfl_xor(vk, 1, 64);
                    float rk = (tq & 1) ? (vk * cv + pk2 * sv) : (vk * cv - pk2 * sv);
                    *(unsigned short*)(smem + RS(kb, t, tq * 2)) = f2bf(rk);
                }
            } else {                           // dims 32..63: pass-through
                #pragma unroll
                for (int r = 0; r < 16; ++r) {
                    int t = (r & 3) + 8 * (r >> 2) + 4 * hf;
                    *(unsigned short*)(smem + RS(qb, t, 64 + tq * 2)) = f2bf(aq[r]);
                    *(unsigned short*)(smem + RS(kb, t, 64 + tq * 2)) = f2bf(ak[r]);
                }
            }
            int vb = V_OFF + hh * 4096;
            int d  = dh * 32 + tq;
            #pragma unroll
            for (int c = 0; c < 4; ++c) {      // regs c*4..c*4+3 = t (c*8+4hf)..+3
                s16x4 pkk;
                pkk[0] = (short)f2bf(av[c * 4 + 0]);
                pkk[1] = (short)f2bf(av[c * 4 + 1]);
                pkk[2] = (short)f2bf(av[c * 4 + 2]);
                pkk[3] = (short)f2bf(av[c * 4 + 3]);
                *(s16x4*)(smem + VS(vb, d, c * 16 + hf * 8)) = pkk;
            }
        }
        __syncthreads();

        // ===== attention (register-only, wave = its own (hh,dh)) ==============
        {
            int qr = Q_OFF + hh * 4096;
            int kr = K_OFF + hh * 4096;
            int vr = V_OFF + hh * 4096;
            f32x16 sc = fz16();
            #pragma unroll
            for (int j = 0; j < 4; ++j) {
                bf16x8 aK = *(const bf16x8*)(smem + RS(kr, tq, j * 32 + hf * 16));
                bf16x8 bQ = *(const bf16x8*)(smem + RS(qr, tq, j * 32 + hf * 16));
                sc = MFMA32(aK, bQ, sc);
            }
            float pe[16];
            float mx = -1e30f;
            #pragma unroll
            for (int r = 0; r < 16; ++r) {
                int tk = (r & 3) + 8 * (r >> 2) + 4 * hf;
                float v = (tk <= tq) ? sc[r] * 0.125f : -1e30f;
                pe[r] = v;
                mx = fmaxf(mx, v);
            }
            mx = fmaxf(mx, __shfl_xor(mx, 32, 64));
            float sum = 0.f;
            #pragma unroll
            for (int r = 0; r < 16; ++r) {
                float e = __expf(pe[r] - mx);
                pe[r] = e;
                sum += e;
            }
            sum += __shfl_xor(sum, 32, 64);
            float inv = 1.f / sum;
            bf16x8 pa0, pa1;
            #pragma unroll
            for (int i2 = 0; i2 < 8; ++i2) {
                pa0[i2] = (short)f2bf(pe[i2] * inv);
                pa1[i2] = (short)f2bf(pe[8 + i2] * inv);
            }
            int d = dh * 32 + tq;
            f32x16 o = fz16();
            {
                s16x4 lo = *(const s16x4*)(smem + VS(vr, d, 8 * hf));
                s16x4 hi = *(const s16x4*)(smem + VS(vr, d, 16 + 8 * hf));
                bf16x8 bv;
                bv[0] = lo[0]; bv[1] = lo[1]; bv[2] = lo[2]; bv[3] = lo[3];
                bv[4] = hi[0]; bv[5] = hi[1]; bv[6] = hi[2]; bv[7] = hi[3];
                o = MFMA32(pa0, bv, o);
            }
            {
                s16x4 lo = *(const s16x4*)(smem + VS(vr, d, 32 + 8 * hf));
                s16x4 hi = *(const s16x4*)(smem + VS(vr, d, 48 + 8 * hf));
                bf16x8 bv;
                bv[0] = lo[0]; bv[1] = lo[1]; bv[2] = lo[2]; bv[3] = lo[3];
                bv[4] = hi[0]; bv[5] = hi[1]; bv[6] = hi[2]; bv[7] = hi[3];
                o = MFMA32(pa1, bv, o);
            }
            #pragma unroll
            for (int r = 0; r < 16; ++r) {
                int t = (r & 3) + 8 * (r >> 2) + 4 * hf;
                *(unsigned short*)(smem + PS(t, (hh * 64 + d) * 2)) = f2bf(o[r]);
            }
        }
        __syncthreads();

        // ===== out-projection: wave = 4 col-tiles, K-slice = this head pair ===
        {
            #pragma unroll
            for (int ksl = 0; ksl < 8; ++ksl) {
                int ksg = it * 8 + ksl;
                bf16x8 a = *(const bf16x8*)(smem + PS(tq, ksl * 32 + hf * 16));
                #pragma unroll
                for (int j = 0; j < 4; ++j) {
                    int ct = wv + 4 * j;
                    bf16x8 bw = *(const bf16x8*)(wof + ((long)(ct * 32 + ksg)) * 512 + lane * 8);
                    oac[j] = MFMA32(a, bw, oac[j]);
                }
            }
        }
        // no barrier: next-iter qkv writes Q/K/V (readers done at attn barrier);
        // next-iter attn writes PV only after next qkv barrier.
    }

    // ===== write out (+bias) =====
    #pragma unroll
    for (int j = 0; j < 4; ++j) {
        int coln = (wv + 4 * j) * 32 + tq;
        float bias = b_out[coln];
        #pragma unroll
        for (int r = 0; r < 16; ++r) {
            int t = (r & 3) + 8 * (r >> 2) + 4 * hf;
            out[base + (long long)t * TSTRIDE + coln] = oac[j][r] + bias;
        }
    }
}

extern "C" void kernel_launch(void* const* d_in, const int* in_sizes, int n_in,
                              void* d_out, int out_size, void* d_ws, size_t ws_size,
                              hipStream_t stream) {
    const float* x     = (const float*)d_in[0];
    const float* w_qkv = (const float*)d_in[1];
    const float* w_out = (const float*)d_in[2];
    const float* b_out = (const float*)d_in[3];
    float* out = (float*)d_out;
    (void)in_sizes; (void)n_in; (void)out_size; (void)ws_size;

    unsigned short* ws = (unsigned short*)d_ws;   // ~2.1 MB

    taa_prep<<<dim3(4098), dim3(256), 0, stream>>>(w_qkv, w_out, ws);
    taa_main<<<dim3(2048), dim3(256), LDS_SZ, stream>>>(x, ws, b_out, out);
}

// Round 13
// 233.183 us; speedup vs baseline: 2.7558x; 2.7558x over previous
//
#include <hip/hip_runtime.h>
#include <hip/hip_bf16.h>
#include <math.h>

#define HEADS  8
#define TT     32
#define DMODEL 512
#define HWSZ   1024
#define TSTRIDE (HWSZ*DMODEL)

#define NQKV (3*DMODEL*DMODEL)   // 786432
#define NOUT (DMODEL*DMODEL)     // 262144
#define NTAB 512

typedef __attribute__((ext_vector_type(8)))  short bf16x8;
typedef __attribute__((ext_vector_type(16))) float f32x16;
typedef __attribute__((ext_vector_type(4)))  short s16x4;
typedef __attribute__((ext_vector_type(2)))  unsigned int u32x2;

__device__ __forceinline__ unsigned short f2bf(float f) {   // RNE f32->bf16
    unsigned int u = __builtin_bit_cast(unsigned int, f);
    u += 0x7FFFu + ((u >> 16) & 1u);
    return (unsigned short)(u >> 16);
}

__device__ __forceinline__ unsigned int pk_bf(float a, float b) {  // low=a, high=b
    return (unsigned int)f2bf(a) | ((unsigned int)f2bf(b) << 16);
}

__device__ __forceinline__ f32x16 fz16() {
    f32x16 v = {0.f,0.f,0.f,0.f,0.f,0.f,0.f,0.f,0.f,0.f,0.f,0.f,0.f,0.f,0.f,0.f};
    return v;
}

// ---------------- prep: weights -> bf16 MFMA16-fragment order + rope tables ----
// (verbatim from the passing 239us round-5 kernel)
__global__ __launch_bounds__(256)
void taa_prep(const float* __restrict__ wqkv, const float* __restrict__ wout,
              unsigned short* __restrict__ ws) {
    long i = (long)blockIdx.x * 256 + threadIdx.x;
    unsigned short* wqf = ws;
    unsigned short* wof = ws + NQKV;
    float* cs = (float*)(wof + NOUT);
    float* sn = cs + NTAB;
    if (i < NQKV) {
        int i8 = (int)(i & 7), lane = (int)((i >> 3) & 63), blk = (int)(i >> 9);
        int k05 = blk & 15, t = blk >> 4;
        int n = t * 16 + (lane & 15);
        int k = k05 * 32 + (lane >> 4) * 8 + i8;
        wqf[i] = f2bf(wqkv[(long)k * 1536 + n]);
    } else if (i < NQKV + NOUT) {
        long j = i - NQKV;
        int i8 = (int)(j & 7), lane = (int)((j >> 3) & 63), blk = (int)(j >> 9);
        int k05 = blk & 15, t = blk >> 4;
        int col = t * 16 + (lane & 15);
        int k = k05 * 32 + (lane >> 4) * 8 + i8;
        wof[j] = f2bf(wout[(long)k * 512 + col]);
    } else if (i < NQKV + NOUT + NTAB) {
        int j = (int)(i - NQKV - NOUT);
        int t = j >> 4, f = j & 15;
        float inv = powf(10000.f, -(float)(2 * f) / 32.f);
        float sv, cv;
        sincosf((float)t * inv, &sv, &cv);
        cs[j] = cv; sn[j] = sv;
    }
}

// ---------------- LDS layout (bytes) — identical to round 5 -------------------
#define X_OFF  0
#define Q_OFF  65536
#define K_OFF  81920
#define V_OFF  98304
#define PV_OFF 114688
#define CS_OFF 131072
#define SN_OFF 133120
#define LDS_SZ 135168

#define XS(g, r, cB) (X_OFF + ((g) << 15) + ((r) << 10) + ((cB) ^ (((r) & 7) << 4)))
#define RS(base, r, cB) ((base) + ((r) << 7) + ((cB) ^ (((r) & 7) << 4)))
#define VS(base, d, cB) ((base) + ((d) << 6) + ((cB) ^ (((d) & 7) << 3)))

#define MFMA16(a, b, c) __builtin_amdgcn_mfma_f32_16x16x32_bf16((a), (b), (c), 0, 0, 0)
#define MFMA32(a, b, c) __builtin_amdgcn_mfma_f32_32x32x16_bf16((a), (b), (c), 0, 0, 0)

__global__ __launch_bounds__(512, 1)
void taa_main(const float* __restrict__ x,
              const unsigned short* __restrict__ ws,
              const float* __restrict__ b_out,
              float* __restrict__ out) {
    extern __shared__ __align__(16) unsigned char smem[];

    const unsigned short* wqf = ws;
    const unsigned short* wof = ws + NQKV;
    const float* cs_gl = (const float*)(wof + NOUT);
    const float* sn_gl = cs_gl + NTAB;

    const int tid  = threadIdx.x;
    const int lane = tid & 63;
    const int wv   = tid >> 6;                 // wave 0..7
    const int quad = lane >> 4;
    const int lid  = lane & 15;

    const int n0 = blockIdx.x * 2;
    const long long base0 = ((long long)(n0 >> 10) * (TT * HWSZ) + (n0 & 1023)) * DMODEL;
    const int n1 = n0 + 1;
    const long long base1 = ((long long)(n1 >> 10) * (TT * HWSZ) + (n1 & 1023)) * DMODEL;

    float* cs_l = (float*)(smem + CS_OFF);
    float* sn_l = (float*)(smem + SN_OFF);
    for (int i = tid; i < NTAB; i += 512) { cs_l[i] = cs_gl[i]; sn_l[i] = sn_gl[i]; }

    // ---- stage x (both groups): fp32 global -> bf16 swizzled LDS ----
    for (int idx = tid; idx < 4096; idx += 512) {
        int g  = idx >> 11;
        int r  = (idx >> 6) & 31;
        int c8 = idx & 63;
        long long bg = g ? base1 : base0;
        const float4* src = (const float4*)(x + bg + (long long)r * TSTRIDE + c8 * 8);
        float4 f0 = src[0], f1 = src[1];
        s16x4 lo, hi;
        lo[0] = (short)f2bf(f0.x); lo[1] = (short)f2bf(f0.y);
        lo[2] = (short)f2bf(f0.z); lo[3] = (short)f2bf(f0.w);
        hi[0] = (short)f2bf(f1.x); hi[1] = (short)f2bf(f1.y);
        hi[2] = (short)f2bf(f1.z); hi[3] = (short)f2bf(f1.w);
        int a = XS(g, r, c8 * 16);
        *(s16x4*)(smem + a)     = lo;
        *(s16x4*)(smem + a + 8) = hi;
    }

    typedef __attribute__((ext_vector_type(4))) float f32x4;
    f32x4 oacc[4][2][2];                       // [col-tile j][group][row-tile]
    #pragma unroll
    for (int j = 0; j < 4; ++j)
        #pragma unroll
        for (int g = 0; g < 2; ++g)
            #pragma unroll
            for (int mt = 0; mt < 2; ++mt) oacc[j][g][mt] = (f32x4){0.f, 0.f, 0.f, 0.f};

    __syncthreads();

    for (int it = 0; it < 4; ++it) {           // 2 heads per iteration
        const int hpair = it * 2;

        // ===== qkv GEMM: 24 col-tiles (2 heads), 3 balanced rounds — r5 verbatim =
        for (int rnd = 0; rnd < 3; ++rnd) {
            int ct  = rnd * 8 + wv;            // 0..23
            int m   = ct >> 3;                 // 0=q 1=k 2=v
            int hh  = (ct >> 2) & 1;
            int t16 = ct & 3;
            int T   = m * 32 + (hpair + hh) * 4 + t16;
            const unsigned short* wp = wqf + ((long)T * 16) * 512 + lane * 8;
            f32x4 acc[2][2];
            #pragma unroll
            for (int g = 0; g < 2; ++g)
                #pragma unroll
                for (int mt = 0; mt < 2; ++mt) acc[g][mt] = (f32x4){0.f, 0.f, 0.f, 0.f};
            #pragma unroll 4
            for (int k05 = 0; k05 < 16; ++k05) {
                bf16x8 bw = *(const bf16x8*)(wp + (long)k05 * 512);
                #pragma unroll
                for (int g = 0; g < 2; ++g)
                    #pragma unroll
                    for (int mt = 0; mt < 2; ++mt) {
                        bf16x8 a = *(const bf16x8*)(smem + XS(g, lid + 16 * mt, k05 * 64 + quad * 16));
                        acc[g][mt] = MFMA16(a, bw, acc[g][mt]);
                    }
            }
            if (m < 2) {                       // q,k: row-major [t][64] with RoPE
                int dstb = ((m == 0) ? Q_OFF : K_OFF) + hh * 4096;
                if (t16 < 2) {                 // rotary cols 0..31
                    #pragma unroll
                    for (int g = 0; g < 2; ++g)
                        #pragma unroll
                        for (int mt = 0; mt < 2; ++mt)
                            #pragma unroll
                            for (int r = 0; r < 4; ++r) {
                                float v = acc[g][mt][r];
                                float p = __shfl_xor(v, 1, 64);
                                int trow = mt * 16 + quad * 4 + r;
                                int colh = t16 * 16 + lid;
                                int jj = colh >> 1;
                                float cv = cs_l[trow * 16 + jj];
                                float sv = sn_l[trow * 16 + jj];
                                float res = (colh & 1) ? (v * cv + p * sv) : (v * cv - p * sv);
                                *(unsigned short*)(smem + RS(dstb + g * 8192, trow, colh * 2)) = f2bf(res);
                            }
                } else {
                    #pragma unroll
                    for (int g = 0; g < 2; ++g)
                        #pragma unroll
                        for (int mt = 0; mt < 2; ++mt)
                            #pragma unroll
                            for (int r = 0; r < 4; ++r) {
                                int trow = mt * 16 + quad * 4 + r;
                                *(unsigned short*)(smem + RS(dstb + g * 8192, trow, (t16 * 16 + lid) * 2)) = f2bf(acc[g][mt][r]);
                            }
                }
            } else {                           // v -> V^T [64 d][32 t]
                #pragma unroll
                for (int g = 0; g < 2; ++g)
                    #pragma unroll
                    for (int mt = 0; mt < 2; ++mt) {
                        int d  = t16 * 16 + lid;
                        int t0 = mt * 16 + quad * 4;
                        s16x4 pk;
                        pk[0] = (short)f2bf(acc[g][mt][0]); pk[1] = (short)f2bf(acc[g][mt][1]);
                        pk[2] = (short)f2bf(acc[g][mt][2]); pk[3] = (short)f2bf(acc[g][mt][3]);
                        *(s16x4*)(smem + VS(V_OFF + (g * 2 + hh) * 4096, d, t0 * 2)) = pk;
                    }
            }
        }
        __syncthreads();

        // ===== attention: r5 verbatim except PV operand swap + packed store =====
        {
            int g  = wv >> 2;
            int hh = (wv >> 1) & 1;
            int dt = wv & 1;
            int qr  = Q_OFF  + (g * 2 + hh) * 4096;
            int kr  = K_OFF  + (g * 2 + hh) * 4096;
            int vr  = V_OFF  + (g * 2 + hh) * 4096;
            int pvr = PV_OFF + (g * 2 + hh) * 4096;
            int tq = lane & 31;
            int hf = lane >> 5;

            // S^T = K · Q^T
            f32x16 sc = fz16();
            #pragma unroll
            for (int j = 0; j < 4; ++j) {
                bf16x8 aK = *(const bf16x8*)(smem + RS(kr, tq, j * 32 + hf * 16));
                bf16x8 bQ = *(const bf16x8*)(smem + RS(qr, tq, j * 32 + hf * 16));
                sc = MFMA32(aK, bQ, sc);
            }
            float pe[16];
            float mx = -1e30f;
            #pragma unroll
            for (int r = 0; r < 16; ++r) {
                int tk = (r & 3) + 8 * (r >> 2) + 4 * hf;
                float v = (tk <= tq) ? sc[r] * 0.125f : -1e30f;
                pe[r] = v;
                mx = fmaxf(mx, v);
            }
            mx = fmaxf(mx, __shfl_xor(mx, 32, 64));
            float sum = 0.f;
            #pragma unroll
            for (int r = 0; r < 16; ++r) {
                float e = __expf(pe[r] - mx);
                pe[r] = e;
                sum += e;
            }
            sum += __shfl_xor(sum, 32, 64);
            float inv = 1.f / sum;
            bf16x8 pa0, pa1;
            #pragma unroll
            for (int i2 = 0; i2 < 8; ++i2) {
                pa0[i2] = (short)f2bf(pe[i2] * inv);
                pa1[i2] = (short)f2bf(pe[8 + i2] * inv);
            }
            // PV, SWAPPED operands (bisect: the only change vs round-5):
            // A = V-frag (A[m]=V[sigma(k)][dt*32+m]), B = P (B[k][n]=P[tq=n][sigma(k)])
            // -> D[m][n] = O[tq=n][d=dt*32+m]; lane owns row tq, 4-consecutive-d runs.
            int d = dt * 32 + tq;
            f32x16 o = fz16();
            {
                s16x4 lo = *(const s16x4*)(smem + VS(vr, d, 8 * hf));
                s16x4 hi = *(const s16x4*)(smem + VS(vr, d, 16 + 8 * hf));
                bf16x8 bv;
                bv[0] = lo[0]; bv[1] = lo[1]; bv[2] = lo[2]; bv[3] = lo[3];
                bv[4] = hi[0]; bv[5] = hi[1]; bv[6] = hi[2]; bv[7] = hi[3];
                o = MFMA32(bv, pa0, o);
            }
            {
                s16x4 lo = *(const s16x4*)(smem + VS(vr, d, 32 + 8 * hf));
                s16x4 hi = *(const s16x4*)(smem + VS(vr, d, 48 + 8 * hf));
                bf16x8 bv;
                bv[0] = lo[0]; bv[1] = lo[1]; bv[2] = lo[2]; bv[3] = lo[3];
                bv[4] = hi[0]; bv[5] = hi[1]; bv[6] = hi[2]; bv[7] = hi[3];
                o = MFMA32(bv, pa1, o);
            }
            // packed PV store: row tq; o[4c+j] = O[tq][dt*32 + 8c + 4hf + j]
            #pragma unroll
            for (int c = 0; c < 4; ++c) {
                u32x2 pk2;
                pk2[0] = pk_bf(o[4 * c + 0], o[4 * c + 1]);
                pk2[1] = pk_bf(o[4 * c + 2], o[4 * c + 3]);
                int db = dt * 32 + c * 8 + 4 * hf;
                *(u32x2*)(smem + RS(pvr, tq, db * 2)) = pk2;
            }
        }
        __syncthreads();

        // ===== out-projection accumulate — r5 verbatim ==========================
        {
            #pragma unroll
            for (int k05h = 0; k05h < 4; ++k05h) {
                int hh   = k05h >> 1;
                int dblk = k05h & 1;
                int kb   = (hpair + hh) * 2 + dblk;
                bf16x8 a[2][2];
                #pragma unroll
                for (int g = 0; g < 2; ++g)
                    #pragma unroll
                    for (int mt = 0; mt < 2; ++mt)
                        a[g][mt] = *(const bf16x8*)(smem + RS(PV_OFF + (g * 2 + hh) * 4096, lid + 16 * mt, dblk * 64 + quad * 16));
                #pragma unroll
                for (int j = 0; j < 4; ++j) {
                    int ct = wv + 8 * j;
                    bf16x8 bw = *(const bf16x8*)(wof + ((long)(ct * 16 + kb)) * 512 + lane * 8);
                    #pragma unroll
                    for (int g = 0; g < 2; ++g)
                        #pragma unroll
                        for (int mt = 0; mt < 2; ++mt)
                            oacc[j][g][mt] = MFMA16(a[g][mt], bw, oacc[j][g][mt]);
                }
            }
        }
        // no barrier: next-iter qkv writes Q/K/V (readers synced at attn barrier);
        // next-iter attn writes PV only after next qkv barrier.
    }

    // ===== write out (+bias) — r5 verbatim =====
    #pragma unroll
    for (int j = 0; j < 4; ++j) {
        int col = (wv + 8 * j) * 16 + lid;
        float bias = b_out[col];
        #pragma unroll
        for (int g = 0; g < 2; ++g) {
            long long bg = g ? base1 : base0;
            #pragma unroll
            for (int mt = 0; mt < 2; ++mt)
                #pragma unroll
                for (int r = 0; r < 4; ++r) {
                    int t = mt * 16 + quad * 4 + r;
                    out[bg + (long long)t * TSTRIDE + col] = oacc[j][g][mt][r] + bias;
                }
        }
    }
}

extern "C" void kernel_launch(void* const* d_in, const int* in_sizes, int n_in,
                              void* d_out, int out_size, void* d_ws, size_t ws_size,
                              hipStream_t stream) {
    const float* x     = (const float*)d_in[0];
    const float* w_qkv = (const float*)d_in[1];
    const float* w_out = (const float*)d_in[2];
    const float* b_out = (const float*)d_in[3];
    float* out = (float*)d_out;
    (void)in_sizes; (void)n_in; (void)out_size; (void)ws_size;

    unsigned short* ws = (unsigned short*)d_ws;   // ~2.1 MB

    taa_prep<<<dim3(4098), dim3(256), 0, stream>>>(w_qkv, w_out, ws);
    taa_main<<<dim3(1024), dim3(512), LDS_SZ, stream>>>(x, ws, b_out, out);
}